// Round 2
// baseline (8391.159 us; speedup 1.0000x reference)
//
#include <hip/hip_runtime.h>

// Problem constants (fixed by reference setup_inputs)
#define NB    16              // batch
#define CIN_  64              // input channels of x
#define COUT_ 128             // channels of z / output
#define PLANE_ 1024           // 32*32
#define DDIM  (COUT_*PLANE_)  // 131072
#define BDTOT ((size_t)NB*DDIM) // 2097152
#define KMAX  20              // Broyden threshold

// bf16 <-> fp32 helpers (RNE)
__device__ __forceinline__ float bf2f(unsigned short h) {
    return __uint_as_float(((unsigned int)h) << 16);
}
__device__ __forceinline__ unsigned short f2bf(float f) {
    unsigned int u = __float_as_uint(f);
    u = (u + 0x7FFFu + ((u >> 16) & 1u)) >> 16;
    return (unsigned short)u;
}

// ---------------------------------------------------------------------------
// Direct 3x3 SAME conv, one (n,co) output plane per block, 256 threads,
// 4 outputs (consecutive w) per thread, input plane staged in LDS with halo.
// MODE 0: out = conv(in,wgt) + bias[co]                    (ux computation)
// MODE 1: g   = relu(conv(in,wgt)+ux) - in ; dgx = g - gx_old  (gx in-place ok)
// MODE 2: out = relu(conv(in,wgt)+ux)                      (final recompute)
// ---------------------------------------------------------------------------
template<int MODE, int CINT>
__global__ __launch_bounds__(256) void conv3x3_kernel(
    const float* __restrict__ in,      // [NB, CINT, 32, 32]
    const float* __restrict__ wgt,     // [COUT_, CINT, 3, 3]
    const float* __restrict__ bias,    // [COUT_]          (MODE 0)
    const float* __restrict__ ux,      // [NB,COUT_,32,32] (MODE 1,2)
    const float* gx_old,               // (MODE 1) may alias out
    float* out,                        // may alias gx_old (MODE 1)
    float* __restrict__ dgx)           // (MODE 1)
{
    __shared__ float sm[34 * 40];      // input plane + 1-halo, row stride 40
    const int bx  = blockIdx.x;        // grid.x = NB*COUT_
    const int n   = bx / COUT_;
    const int co  = bx - n * COUT_;
    const int tid = threadIdx.x;
    const int h   = tid >> 3;          // 0..31 output row
    const int w0  = (tid & 7) << 2;    // 0,4,...,28 first output col

    float acc0 = 0.f, acc1 = 0.f, acc2 = 0.f, acc3 = 0.f;
    const float* inN = in  + (size_t)n * CINT * PLANE_;
    const float* wCo = wgt + (size_t)co * CINT * 9;

    for (int ci = 0; ci < CINT; ++ci) {
        __syncthreads();
        const float* plane = inN + (size_t)ci * PLANE_;
        for (int idx = tid; idx < 34 * 34; idx += 256) {
            int r = idx / 34;
            int c = idx - r * 34;
            int gr = r - 1, gc = c - 1;
            float v = 0.f;
            if ((unsigned)gr < 32u && (unsigned)gc < 32u) v = plane[(gr << 5) + gc];
            sm[r * 40 + c] = v;        // sm[r][c] = input[r-1][c-1]
        }
        __syncthreads();
        const float* wci = wCo + ci * 9;
        float wv[9];
        #pragma unroll
        for (int j = 0; j < 9; ++j) wv[j] = wci[j];   // wave-uniform -> s_load
        #pragma unroll
        for (int kh = 0; kh < 3; ++kh) {
            const float* row = &sm[(h + kh) * 40 + w0];
            float v0 = row[0], v1 = row[1], v2 = row[2];
            float v3 = row[3], v4 = row[4], v5 = row[5];
            float wa = wv[kh * 3 + 0], wb = wv[kh * 3 + 1], wc = wv[kh * 3 + 2];
            acc0 = fmaf(wa, v0, fmaf(wb, v1, fmaf(wc, v2, acc0)));
            acc1 = fmaf(wa, v1, fmaf(wb, v2, fmaf(wc, v3, acc1)));
            acc2 = fmaf(wa, v2, fmaf(wb, v3, fmaf(wc, v4, acc2)));
            acc3 = fmaf(wa, v3, fmaf(wb, v4, fmaf(wc, v5, acc3)));
        }
    }

    size_t o = ((size_t)n * COUT_ + co) * PLANE_ + (h << 5) + w0;
    float a4[4] = {acc0, acc1, acc2, acc3};
    if (MODE == 0) {
        float bb = bias[co];
        #pragma unroll
        for (int j = 0; j < 4; ++j) out[o + j] = a4[j] + bb;
    } else if (MODE == 1) {
        #pragma unroll
        for (int j = 0; j < 4; ++j) {
            float tv = a4[j] + ux[o + j];
            tv = tv > 0.f ? tv : 0.f;
            float g = tv - in[o + j];         // in == z (CINT==COUT_ here)
            float go = gx_old[o + j];         // read BEFORE aliased write
            out[o + j] = g;
            dgx[o + j] = g - go;
        }
    } else {
        #pragma unroll
        for (int j = 0; j < 4; ++j) {
            float tv = a4[j] + ux[o + j];
            out[o + j] = tv > 0.f ? tv : 0.f;
        }
    }
}

// ---------------------------------------------------------------------------
__global__ __launch_bounds__(256) void fill0_kernel(float* __restrict__ a)
{
    size_t i = ((size_t)blockIdx.x * 256 + threadIdx.x) * 4;
    *(float4*)(a + i) = make_float4(0.f, 0.f, 0.f, 0.f);
}

// g(0) = relu(ux); also seeds update = gx0.
__global__ __launch_bounds__(256) void ew_init_kernel(
    const float* __restrict__ ux, float* __restrict__ gx, float* __restrict__ upd)
{
    size_t i = ((size_t)blockIdx.x * 256 + threadIdx.x) * 4;
    float4 u = *(const float4*)(ux + i);
    float4 r;
    r.x = u.x > 0.f ? u.x : 0.f;
    r.y = u.y > 0.f ? u.y : 0.f;
    r.z = u.z > 0.f ? u.z : 0.f;
    r.w = u.w > 0.f ? u.w : 0.f;
    *(float4*)(gx + i)  = r;
    *(float4*)(upd + i) = r;
}

// x += upd  (in place)
__global__ __launch_bounds__(256) void axpy_inplace_kernel(
    float* x, const float* __restrict__ u)
{
    size_t i = ((size_t)blockIdx.x * 256 + threadIdx.x) * 4;
    float4 a = *(const float4*)(x + i);
    float4 b = *(const float4*)(u + i);
    *(float4*)(x + i) = make_float4(a.x + b.x, a.y + b.y, a.z + b.z, a.w + b.w);
}

// ---------------------------------------------------------------------------
// Batched dots. grid = (NB, modes). Deterministic one-block-per-dot.
// y<k      : p_i  = u_i . dx
// y<2k     : q_i = v_i . dgx ; t_i = v_i . gx_new
// y==2k    : dd  = dx . dgx  ; dg1 = dx . gx_new
// y==2k+1  : objpart[b] = gx_new . gx_new            (also the only_obj mode)
// Us/VTs stored bf16, [K][NB][D].
// ---------------------------------------------------------------------------
__global__ __launch_bounds__(256) void dots_kernel(
    const unsigned short* __restrict__ Us, const unsigned short* __restrict__ VTs,
    const float* __restrict__ dx, const float* __restrict__ dgx,
    const float* __restrict__ gxn,
    float* __restrict__ p, float* __restrict__ q, float* __restrict__ t,
    float* __restrict__ dd, float* __restrict__ dg1, float* __restrict__ objpart,
    int k, int only_obj)
{
    const int b = blockIdx.x;
    const int y = blockIdx.y;
    const int tid = threadIdx.x;
    const size_t base = (size_t)b * DDIM;
    const float4* dx4  = (const float4*)(dx + base);
    const float4* dgx4 = (const float4*)(dgx + base);
    const float4* gxn4 = (const float4*)(gxn + base);
    const int N4 = DDIM / 4;

    int mode, i = 0;
    if (only_obj)          mode = 3;
    else if (y < k)        { mode = 0; i = y; }
    else if (y < 2 * k)    { mode = 1; i = y - k; }
    else if (y == 2 * k)   mode = 2;
    else                   mode = 3;

    float s0 = 0.f, s1 = 0.f;
    if (mode == 0) {
        const ushort4* u4 = (const ushort4*)(Us + (size_t)i * BDTOT + base);
        for (int j = tid; j < N4; j += 256) {
            ushort4 a = u4[j]; float4 x = dx4[j];
            s0 += bf2f(a.x) * x.x + bf2f(a.y) * x.y + bf2f(a.z) * x.z + bf2f(a.w) * x.w;
        }
    } else if (mode == 1) {
        const ushort4* v4 = (const ushort4*)(VTs + (size_t)i * BDTOT + base);
        for (int j = tid; j < N4; j += 256) {
            ushort4 a = v4[j]; float4 g = dgx4[j], gg = gxn4[j];
            float a0 = bf2f(a.x), a1 = bf2f(a.y), a2 = bf2f(a.z), a3 = bf2f(a.w);
            s0 += a0 * g.x + a1 * g.y + a2 * g.z + a3 * g.w;
            s1 += a0 * gg.x + a1 * gg.y + a2 * gg.z + a3 * gg.w;
        }
    } else if (mode == 2) {
        for (int j = tid; j < N4; j += 256) {
            float4 a = dx4[j], g = dgx4[j], gg = gxn4[j];
            s0 += a.x * g.x + a.y * g.y + a.z * g.z + a.w * g.w;
            s1 += a.x * gg.x + a.y * gg.y + a.z * gg.z + a.w * gg.w;
        }
    } else {
        for (int j = tid; j < N4; j += 256) {
            float4 gg = gxn4[j];
            s0 += gg.x * gg.x + gg.y * gg.y + gg.z * gg.z + gg.w * gg.w;
        }
    }

    __shared__ float r0[256], r1[256];
    r0[tid] = s0; r1[tid] = s1;
    __syncthreads();
    for (int s = 128; s > 0; s >>= 1) {
        if (tid < s) { r0[tid] += r0[tid + s]; r1[tid] += r1[tid + s]; }
        __syncthreads();
    }
    if (tid == 0) {
        if (mode == 0)      p[b * KMAX + i] = r0[0];
        else if (mode == 1) { q[b * KMAX + i] = r0[0]; t[b * KMAX + i] = r1[0]; }
        else if (mode == 2) { dd[b] = r0[0]; dg1[b] = r1[0]; }
        else                objpart[b] = r0[0];
    }
}

// ---------------------------------------------------------------------------
// Tiny per-iteration scalar math.
// denom = -dx.dgx + sum p_i q_i  (== vT.dgx), clamp |.|<1e-9 -> 1e-9
// r_k   = -dx.gx  + sum p_i t_i  (== vT.gx),  c = r_k/denom
// obj tracking: flag = (||gx||^2 < best^2), best = min.
// phase 0: init best from objpart. phase 1: full. phase 2: obj/flag only.
// ---------------------------------------------------------------------------
__global__ void small_kernel(
    const float* __restrict__ p, const float* __restrict__ q, const float* __restrict__ t,
    const float* __restrict__ dd, const float* __restrict__ dg1,
    const float* __restrict__ objpart,
    float* __restrict__ denom, float* __restrict__ c,
    float* __restrict__ best2, float* __restrict__ flag,
    int k, int phase)
{
    const int tid = threadIdx.x;
    if (phase == 1 && tid < NB) {
        float pq = 0.f, pt = 0.f;
        for (int i = 0; i < k; ++i) {
            pq += p[tid * KMAX + i] * q[tid * KMAX + i];
            pt += p[tid * KMAX + i] * t[tid * KMAX + i];
        }
        float den = -dd[tid] + pq;
        if (fabsf(den) < 1e-9f) den = 1e-9f;
        float rk = -dg1[tid] + pt;
        denom[tid] = den;
        c[tid] = rk / den;
    }
    if (tid == 0) {
        float o = 0.f;
        for (int b = 0; b < NB; ++b) o += objpart[b];
        if (phase == 0) { *best2 = o; *flag = 0.f; }
        else {
            float bo = *best2;
            *flag = (o < bo) ? 1.f : 0.f;
            if (o < bo) *best2 = o;
        }
    }
}

// ---------------------------------------------------------------------------
// Fused big pass: one read of Us/VTs rows [0,k).
// v_k = -dx + sum p_i v_i
// u_k = (dx + dgx - sum q_i u_i) / denom
// upd_new = gx - c*(dx+dgx) - sum t_i u_i + c * sum q_i u_i   (in place: upd==dx)
// grid = (D/1024, NB), 4 elems/thread.
// ---------------------------------------------------------------------------
__global__ __launch_bounds__(256) void pass2_kernel(
    unsigned short* __restrict__ Us, unsigned short* __restrict__ VTs,
    float* upd,                        // in: dx, out: next update (in place)
    const float* __restrict__ dgx, const float* __restrict__ gxn,
    const float* __restrict__ p, const float* __restrict__ q, const float* __restrict__ t,
    const float* __restrict__ denom, const float* __restrict__ c, int k)
{
    const int b = blockIdx.y;
    const int tid = threadIdx.x;
    __shared__ float sp[KMAX], sq[KMAX], st[KMAX];
    __shared__ float sden, sc;
    if (tid < k) {
        sp[tid] = p[b * KMAX + tid];
        sq[tid] = q[b * KMAX + tid];
        st[tid] = t[b * KMAX + tid];
    }
    if (tid == 0) { sden = denom[b]; sc = c[b]; }
    __syncthreads();

    const size_t base = (size_t)b * DDIM + ((size_t)blockIdx.x * 256 + tid) * 4;
    float4 vdx = *(const float4*)(upd + base);
    float4 vdg = *(const float4*)(dgx + base);
    float4 vg  = *(const float4*)(gxn + base);
    float xd[4] = {vdx.x, vdx.y, vdx.z, vdx.w};
    float dg[4] = {vdg.x, vdg.y, vdg.z, vdg.w};
    float gx[4] = {vg.x, vg.y, vg.z, vg.w};
    float S1[4] = {0,0,0,0}, S2[4] = {0,0,0,0}, SV[4] = {0,0,0,0};

    for (int i = 0; i < k; ++i) {
        ushort4 uu = *(const ushort4*)(Us  + (size_t)i * BDTOT + base);
        ushort4 vv = *(const ushort4*)(VTs + (size_t)i * BDTOT + base);
        float u0 = bf2f(uu.x), u1 = bf2f(uu.y), u2 = bf2f(uu.z), u3 = bf2f(uu.w);
        float v0 = bf2f(vv.x), v1 = bf2f(vv.y), v2 = bf2f(vv.z), v3 = bf2f(vv.w);
        float qi = sq[i], ti = st[i], pi = sp[i];
        S1[0] += qi * u0; S1[1] += qi * u1; S1[2] += qi * u2; S1[3] += qi * u3;
        S2[0] += ti * u0; S2[1] += ti * u1; S2[2] += ti * u2; S2[3] += ti * u3;
        SV[0] += pi * v0; SV[1] += pi * v1; SV[2] += pi * v2; SV[3] += pi * v3;
    }

    float vk[4], uk[4], up[4];
    #pragma unroll
    for (int j = 0; j < 4; ++j) {
        vk[j] = -xd[j] + SV[j];
        uk[j] = (xd[j] + dg[j] - S1[j]) / sden;
        up[j] = gx[j] - sc * (xd[j] + dg[j]) - S2[j] + sc * S1[j];
    }
    ushort4 vks, uks;
    vks.x = f2bf(vk[0]); vks.y = f2bf(vk[1]); vks.z = f2bf(vk[2]); vks.w = f2bf(vk[3]);
    uks.x = f2bf(uk[0]); uks.y = f2bf(uk[1]); uks.z = f2bf(uk[2]); uks.w = f2bf(uk[3]);
    *(ushort4*)(VTs + (size_t)k * BDTOT + base) = vks;
    *(ushort4*)(Us  + (size_t)k * BDTOT + base) = uks;
    *(float4*)(upd + base) = make_float4(up[0], up[1], up[2], up[3]);
}

__global__ __launch_bounds__(256) void bestcopy_kernel(
    const float* __restrict__ flag, const float* __restrict__ xn, float* __restrict__ best)
{
    if (flag[0] == 0.f) return;
    size_t i = ((size_t)blockIdx.x * 256 + threadIdx.x) * 4;
    *(float4*)(best + i) = *(const float4*)(xn + i);
}

// ---------------------------------------------------------------------------
extern "C" void kernel_launch(void* const* d_in, const int* in_sizes, int n_in,
                              void* d_out, int out_size, void* d_ws, size_t ws_size,
                              hipStream_t stream)
{
    (void)in_sizes; (void)n_in; (void)out_size; (void)ws_size;
    const float* x  = (const float*)d_in[0];   // [16,64,32,32]
    const float* A  = (const float*)d_in[1];   // [128,128,3,3]
    const float* U  = (const float*)d_in[2];   // [128,64,3,3]
    const float* bb = (const float*)d_in[3];   // [128]
    float* out = (float*)d_out;

    char* w = (char*)d_ws;
    size_t off = 0;
    auto alloc = [&](size_t bytes) -> void* {
        void* pp = (void*)(w + off);
        off += (bytes + 255) & ~(size_t)255;
        return pp;
    };
    const size_t BDB = BDTOT * sizeof(float);   // 8 MB
    float* ux    = (float*)alloc(BDB);
    float* xv    = (float*)alloc(BDB);
    float* gx    = (float*)alloc(BDB);
    float* upd   = (float*)alloc(BDB);
    float* dgx   = (float*)alloc(BDB);
    float* bestx = (float*)alloc(BDB);
    unsigned short* Us  = (unsigned short*)alloc((size_t)KMAX * BDTOT * 2); // 84 MB
    unsigned short* VTs = (unsigned short*)alloc((size_t)KMAX * BDTOT * 2); // 84 MB
    float* p     = (float*)alloc(NB * KMAX * sizeof(float));
    float* q     = (float*)alloc(NB * KMAX * sizeof(float));
    float* t     = (float*)alloc(NB * KMAX * sizeof(float));
    float* dd    = (float*)alloc(NB * sizeof(float));
    float* dg1   = (float*)alloc(NB * sizeof(float));
    float* objp  = (float*)alloc(NB * sizeof(float));
    float* denom = (float*)alloc(NB * sizeof(float));
    float* c     = (float*)alloc(NB * sizeof(float));
    float* best2 = (float*)alloc(sizeof(float));
    float* flag  = (float*)alloc(sizeof(float));
    // total: 48 MB state + 168 MB history + ~3 KB  (~216 MB)

    const int EWG = (int)(BDTOT / (256 * 4));   // 2048
    const dim3 CG(NB * COUT_);                  // 2048 conv blocks

    fill0_kernel<<<EWG, 256, 0, stream>>>(xv);     // x0 = 0
    fill0_kernel<<<EWG, 256, 0, stream>>>(bestx);  // best_x = x0

    // ux = conv(x,U) + b
    conv3x3_kernel<0, CIN_><<<CG, 256, 0, stream>>>(x, U, bb, nullptr, nullptr, ux, nullptr);
    // gx0 = relu(ux), update = gx0
    ew_init_kernel<<<EWG, 256, 0, stream>>>(ux, gx, upd);
    // best_obj = ||gx0||^2
    dots_kernel<<<dim3(NB, 1), 256, 0, stream>>>(Us, VTs, upd, dgx, gx,
                                                 p, q, t, dd, dg1, objp, 0, 1);
    small_kernel<<<1, 64, 0, stream>>>(p, q, t, dd, dg1, objp, denom, c, best2, flag, 0, 0);

    for (int k = 0; k < KMAX; ++k) {
        // x += update   (dx == upd, kept)
        axpy_inplace_kernel<<<EWG, 256, 0, stream>>>(xv, upd);
        // gx_new = relu(conv(x,A)+ux) - x ; dgx = gx_new - gx   (gx in place)
        conv3x3_kernel<1, COUT_><<<CG, 256, 0, stream>>>(xv, A, nullptr, ux, gx, gx, dgx);
        if (k < KMAX - 1) {
            dots_kernel<<<dim3(NB, 2 * k + 2), 256, 0, stream>>>(
                Us, VTs, upd, dgx, gx, p, q, t, dd, dg1, objp, k, 0);
            small_kernel<<<1, 64, 0, stream>>>(p, q, t, dd, dg1, objp,
                                               denom, c, best2, flag, k, 1);
            pass2_kernel<<<dim3(EWG / NB, NB), 256, 0, stream>>>(
                Us, VTs, upd, dgx, gx, p, q, t, denom, c, k);
        } else {
            // last iteration: only the objective matters
            dots_kernel<<<dim3(NB, 1), 256, 0, stream>>>(
                Us, VTs, upd, dgx, gx, p, q, t, dd, dg1, objp, k, 1);
            small_kernel<<<1, 64, 0, stream>>>(p, q, t, dd, dg1, objp,
                                               denom, c, best2, flag, k, 2);
        }
        bestcopy_kernel<<<EWG, 256, 0, stream>>>(flag, xv, bestx);
    }

    // zn = relu(conv(best_x,A) + ux)
    conv3x3_kernel<2, COUT_><<<CG, 256, 0, stream>>>(bestx, A, nullptr, ux,
                                                     nullptr, out, nullptr);
}

// Round 3
// 2366.853 us; speedup vs baseline: 3.5453x; 3.5453x over previous
//
#include <hip/hip_runtime.h>

// Problem constants (fixed by reference setup_inputs)
#define NB    16              // batch
#define CIN_  64              // input channels of x
#define COUT_ 128             // channels of z / output
#define PLANE_ 1024           // 32*32
#define DDIM  (COUT_*PLANE_)  // 131072
#define BDTOT ((size_t)NB*DDIM) // 2097152
#define KMAX  20              // Broyden threshold

typedef short  bfrag __attribute__((ext_vector_type(8)));  // 8 bf16 (4 VGPRs)
typedef float  ffrag __attribute__((ext_vector_type(4)));  // 4 fp32 acc

// bf16 <-> fp32 helpers (RNE)
__device__ __forceinline__ float bf2f(unsigned short h) {
    return __uint_as_float(((unsigned int)h) << 16);
}
__device__ __forceinline__ unsigned short f2bf(float f) {
    unsigned int u = __float_as_uint(f);
    u = (u + 0x7FFFu + ((u >> 16) & 1u)) >> 16;
    return (unsigned short)u;
}

// ---------------------------------------------------------------------------
// MFMA implicit-GEMM 3x3 SAME conv over NHWC bf16 input.
//   zb  : [NB][1024 px][CIN] bf16   (input image / iterate mirror)
//   Wt  : [9 taps][128 co][CIN] bf16 (pre-transposed weights)
// One wave (64 thr) computes a 32co x 32px tile; a 32-px tile is one image
// row (h = blockIdx.x), w = col(0..15) and col+16. K = 9 taps x CIN.
// MODE 0: out = conv + bias[co]            -> ux   (fp32 NHWC)
// MODE 1: g = relu(conv+ux) - x ; dgx = g - gx_old  (gx in-place, fp32 NHWC)
// MODE 2: out = relu(conv+ux)              -> out  (fp32 NCHW!)
// grid: (32 px-tiles, 4 co-tiles, NB), block = 64.
// ---------------------------------------------------------------------------
template<int MODE, int CIN>
__global__ __launch_bounds__(64) void mfma_conv_kernel(
    const unsigned short* __restrict__ zb,
    const unsigned short* __restrict__ Wt,
    const float* __restrict__ bias,   // MODE 0
    const float* __restrict__ ux,     // MODE 1,2
    const float* __restrict__ xin,    // MODE 1 (fp32 iterate, NHWC)
    float* gx,                        // MODE 1 out (may alias gx_old), MODE 0/2: out
    float* __restrict__ dgx)          // MODE 1
{
    const int hrow    = blockIdx.x;        // image row 0..31
    const int co_base = blockIdx.y * 32;   // 0,32,64,96
    const int n       = blockIdx.z;
    const int lane    = threadIdx.x;
    const int col     = lane & 15;
    const int quad    = lane >> 4;

    ffrag acc00 = {0.f,0.f,0.f,0.f};  // [m-subtile][n-subtile]
    ffrag acc01 = {0.f,0.f,0.f,0.f};
    ffrag acc10 = {0.f,0.f,0.f,0.f};
    ffrag acc11 = {0.f,0.f,0.f,0.f};
    const bfrag bzero = {0,0,0,0,0,0,0,0};

    const int w0 = col;        // px subtile 0: w = 0..15
    const int w1 = col + 16;   // px subtile 1: w = 16..31
    const size_t zbase = (size_t)n * PLANE_ * CIN;

    #pragma unroll
    for (int tap = 0; tap < 9; ++tap) {
        const int dh = tap / 3 - 1, dw = tap % 3 - 1;
        const int sh = hrow + dh;
        const bool rowok = (unsigned)sh < 32u;
        const int sw0 = w0 + dw, sw1 = w1 + dw;
        const bool v0 = rowok && (unsigned)sw0 < 32u;
        const bool v1 = rowok && (unsigned)sw1 < 32u;
        // clamped source pixel (any in-range addr when invalid; result zeroed)
        const int sp0 = v0 ? (sh * 32 + sw0) : (hrow * 32 + w0);
        const int sp1 = v1 ? (sh * 32 + sw1) : (hrow * 32 + w1);
        const unsigned short* z0 = zb + zbase + (size_t)sp0 * CIN + quad * 8;
        const unsigned short* z1 = zb + zbase + (size_t)sp1 * CIN + quad * 8;
        const unsigned short* wr0 = Wt + ((size_t)tap * COUT_ + co_base + col) * CIN + quad * 8;
        const unsigned short* wr1 = wr0 + 16 * CIN;
        #pragma unroll
        for (int cb = 0; cb < CIN; cb += 32) {
            bfrag a0 = *(const bfrag*)(wr0 + cb);
            bfrag a1 = *(const bfrag*)(wr1 + cb);
            bfrag b0 = *(const bfrag*)(z0 + cb);
            bfrag b1 = *(const bfrag*)(z1 + cb);
            if (!v0) b0 = bzero;
            if (!v1) b1 = bzero;
            acc00 = __builtin_amdgcn_mfma_f32_16x16x32_bf16(a0, b0, acc00, 0, 0, 0);
            acc01 = __builtin_amdgcn_mfma_f32_16x16x32_bf16(a0, b1, acc01, 0, 0, 0);
            acc10 = __builtin_amdgcn_mfma_f32_16x16x32_bf16(a1, b0, acc10, 0, 0, 0);
            acc11 = __builtin_amdgcn_mfma_f32_16x16x32_bf16(a1, b1, acc11, 0, 0, 0);
        }
    }

    // Epilogue. D mapping: col(px) = lane&15, row(co) = quad*4 + reg.
    #pragma unroll
    for (int mt = 0; mt < 2; ++mt) {
        #pragma unroll
        for (int nt = 0; nt < 2; ++nt) {
            ffrag a = (mt == 0) ? (nt == 0 ? acc00 : acc01)
                                : (nt == 0 ? acc10 : acc11);
            const int co = co_base + mt * 16 + quad * 4;           // +reg 0..3
            const int px = hrow * 32 + nt * 16 + col;
            const size_t o = ((size_t)n * PLANE_ + px) * COUT_ + co; // NHWC
            if (MODE == 0) {
                float4 bv = *(const float4*)(bias + co);
                float4 r = {a[0] + bv.x, a[1] + bv.y, a[2] + bv.z, a[3] + bv.w};
                *(float4*)(gx + o) = r;
            } else if (MODE == 1) {
                float4 uv = *(const float4*)(ux + o);
                float4 xv = *(const float4*)(xin + o);
                float4 go = *(const float4*)(gx + o);   // read before aliased write
                float4 g, d;
                float t0 = a[0] + uv.x; t0 = t0 > 0.f ? t0 : 0.f; g.x = t0 - xv.x; d.x = g.x - go.x;
                float t1 = a[1] + uv.y; t1 = t1 > 0.f ? t1 : 0.f; g.y = t1 - xv.y; d.y = g.y - go.y;
                float t2 = a[2] + uv.z; t2 = t2 > 0.f ? t2 : 0.f; g.z = t2 - xv.z; d.z = g.z - go.z;
                float t3 = a[3] + uv.w; t3 = t3 > 0.f ? t3 : 0.f; g.w = t3 - xv.w; d.w = g.w - go.w;
                *(float4*)(gx + o) = g;
                *(float4*)(dgx + o) = d;
            } else {
                float4 uv = *(const float4*)(ux + o);
                // NCHW output: out[n][co+r][px]
                #pragma unroll
                for (int r = 0; r < 4; ++r) {
                    float t = a[r] + (&uv.x)[r];
                    gx[((size_t)n * COUT_ + co + r) * PLANE_ + px] = t > 0.f ? t : 0.f;
                }
            }
        }
    }
}

// ---------------------------------------------------------------------------
// One-time prep: weights OIHW fp32 -> [tap][co][ci] bf16 (A and U),
// and x NCHW fp32 -> NHWC bf16.
// ---------------------------------------------------------------------------
#define NWA (9 * 128 * 128)
#define NWU (9 * 128 * 64)
__global__ __launch_bounds__(256) void prep_w_kernel(
    const float* __restrict__ A, const float* __restrict__ U,
    unsigned short* __restrict__ WA, unsigned short* __restrict__ WU)
{
    int idx = blockIdx.x * 256 + threadIdx.x;
    if (idx < NWA) {
        int tap = idx / (128 * 128), r = idx % (128 * 128);
        int co = r >> 7, ci = r & 127;
        WA[idx] = f2bf(A[(co * 128 + ci) * 9 + tap]);
    } else if (idx < NWA + NWU) {
        int j = idx - NWA;
        int tap = j / (128 * 64), r = j % (128 * 64);
        int co = r >> 6, ci = r & 63;
        WU[j] = f2bf(U[(co * 64 + ci) * 9 + tap]);
    }
}

__global__ __launch_bounds__(256) void prep_xin_kernel(
    const float* __restrict__ x, unsigned short* __restrict__ xb)
{
    int idx = blockIdx.x * 256 + threadIdx.x;   // over 16*1024*64
    int n = idx >> 16, r = idx & 65535;
    int px = r >> 6, ci = r & 63;
    xb[idx] = f2bf(x[(n * 64 + ci) * 1024 + px]);
}

// ---------------------------------------------------------------------------
__global__ __launch_bounds__(256) void fill0_kernel(float* __restrict__ a)
{
    size_t i = ((size_t)blockIdx.x * 256 + threadIdx.x) * 4;
    *(float4*)(a + i) = make_float4(0.f, 0.f, 0.f, 0.f);
}

// g(0) = relu(ux); also seeds update = gx0.
__global__ __launch_bounds__(256) void ew_init_kernel(
    const float* __restrict__ ux, float* __restrict__ gx, float* __restrict__ upd)
{
    size_t i = ((size_t)blockIdx.x * 256 + threadIdx.x) * 4;
    float4 u = *(const float4*)(ux + i);
    float4 r;
    r.x = u.x > 0.f ? u.x : 0.f;
    r.y = u.y > 0.f ? u.y : 0.f;
    r.z = u.z > 0.f ? u.z : 0.f;
    r.w = u.w > 0.f ? u.w : 0.f;
    *(float4*)(gx + i)  = r;
    *(float4*)(upd + i) = r;
}

// x += upd (in place, fp32 NHWC) and write bf16 mirror zb.
__global__ __launch_bounds__(256) void axpy_mirror_kernel(
    float* x, const float* __restrict__ u, unsigned short* __restrict__ zb)
{
    size_t i = ((size_t)blockIdx.x * 256 + threadIdx.x) * 4;
    float4 a = *(const float4*)(x + i);
    float4 b = *(const float4*)(u + i);
    float4 r = {a.x + b.x, a.y + b.y, a.z + b.z, a.w + b.w};
    *(float4*)(x + i) = r;
    ushort4 m;
    m.x = f2bf(r.x); m.y = f2bf(r.y); m.z = f2bf(r.z); m.w = f2bf(r.w);
    *(ushort4*)(zb + i) = m;
}

// ---------------------------------------------------------------------------
// Batched dots. grid = (NB, modes). Deterministic one-block-per-dot.
// y<k      : p_i  = u_i . dx
// y<2k     : q_i = v_i . dgx ; t_i = v_i . gx_new
// y==2k    : dd  = dx . dgx  ; dg1 = dx . gx_new
// y==2k+1  : objpart[b] = gx_new . gx_new            (also the only_obj mode)
// Us/VTs stored bf16, [K][NB][D].
// ---------------------------------------------------------------------------
__global__ __launch_bounds__(256) void dots_kernel(
    const unsigned short* __restrict__ Us, const unsigned short* __restrict__ VTs,
    const float* __restrict__ dx, const float* __restrict__ dgx,
    const float* __restrict__ gxn,
    float* __restrict__ p, float* __restrict__ q, float* __restrict__ t,
    float* __restrict__ dd, float* __restrict__ dg1, float* __restrict__ objpart,
    int k, int only_obj)
{
    const int b = blockIdx.x;
    const int y = blockIdx.y;
    const int tid = threadIdx.x;
    const size_t base = (size_t)b * DDIM;
    const float4* dx4  = (const float4*)(dx + base);
    const float4* dgx4 = (const float4*)(dgx + base);
    const float4* gxn4 = (const float4*)(gxn + base);
    const int N4 = DDIM / 4;

    int mode, i = 0;
    if (only_obj)          mode = 3;
    else if (y < k)        { mode = 0; i = y; }
    else if (y < 2 * k)    { mode = 1; i = y - k; }
    else if (y == 2 * k)   mode = 2;
    else                   mode = 3;

    float s0 = 0.f, s1 = 0.f;
    if (mode == 0) {
        const ushort4* u4 = (const ushort4*)(Us + (size_t)i * BDTOT + base);
        for (int j = tid; j < N4; j += 256) {
            ushort4 a = u4[j]; float4 x = dx4[j];
            s0 += bf2f(a.x) * x.x + bf2f(a.y) * x.y + bf2f(a.z) * x.z + bf2f(a.w) * x.w;
        }
    } else if (mode == 1) {
        const ushort4* v4 = (const ushort4*)(VTs + (size_t)i * BDTOT + base);
        for (int j = tid; j < N4; j += 256) {
            ushort4 a = v4[j]; float4 g = dgx4[j], gg = gxn4[j];
            float a0 = bf2f(a.x), a1 = bf2f(a.y), a2 = bf2f(a.z), a3 = bf2f(a.w);
            s0 += a0 * g.x + a1 * g.y + a2 * g.z + a3 * g.w;
            s1 += a0 * gg.x + a1 * gg.y + a2 * gg.z + a3 * gg.w;
        }
    } else if (mode == 2) {
        for (int j = tid; j < N4; j += 256) {
            float4 a = dx4[j], g = dgx4[j], gg = gxn4[j];
            s0 += a.x * g.x + a.y * g.y + a.z * g.z + a.w * g.w;
            s1 += a.x * gg.x + a.y * gg.y + a.z * gg.z + a.w * gg.w;
        }
    } else {
        for (int j = tid; j < N4; j += 256) {
            float4 gg = gxn4[j];
            s0 += gg.x * gg.x + gg.y * gg.y + gg.z * gg.z + gg.w * gg.w;
        }
    }

    __shared__ float r0[256], r1[256];
    r0[tid] = s0; r1[tid] = s1;
    __syncthreads();
    for (int s = 128; s > 0; s >>= 1) {
        if (tid < s) { r0[tid] += r0[tid + s]; r1[tid] += r1[tid + s]; }
        __syncthreads();
    }
    if (tid == 0) {
        if (mode == 0)      p[b * KMAX + i] = r0[0];
        else if (mode == 1) { q[b * KMAX + i] = r0[0]; t[b * KMAX + i] = r1[0]; }
        else if (mode == 2) { dd[b] = r0[0]; dg1[b] = r1[0]; }
        else                objpart[b] = r0[0];
    }
}

// ---------------------------------------------------------------------------
// Tiny per-iteration scalar math (see R1 comment).
// ---------------------------------------------------------------------------
__global__ void small_kernel(
    const float* __restrict__ p, const float* __restrict__ q, const float* __restrict__ t,
    const float* __restrict__ dd, const float* __restrict__ dg1,
    const float* __restrict__ objpart,
    float* __restrict__ denom, float* __restrict__ c,
    float* __restrict__ best2, float* __restrict__ flag,
    int k, int phase)
{
    const int tid = threadIdx.x;
    if (phase == 1 && tid < NB) {
        float pq = 0.f, pt = 0.f;
        for (int i = 0; i < k; ++i) {
            pq += p[tid * KMAX + i] * q[tid * KMAX + i];
            pt += p[tid * KMAX + i] * t[tid * KMAX + i];
        }
        float den = -dd[tid] + pq;
        if (fabsf(den) < 1e-9f) den = 1e-9f;
        float rk = -dg1[tid] + pt;
        denom[tid] = den;
        c[tid] = rk / den;
    }
    if (tid == 0) {
        float o = 0.f;
        for (int b = 0; b < NB; ++b) o += objpart[b];
        if (phase == 0) { *best2 = o; *flag = 0.f; }
        else {
            float bo = *best2;
            *flag = (o < bo) ? 1.f : 0.f;
            if (o < bo) *best2 = o;
        }
    }
}

// ---------------------------------------------------------------------------
// Fused big pass: one read of Us/VTs rows [0,k).
// v_k = -dx + sum p_i v_i
// u_k = (dx + dgx - sum q_i u_i) / denom
// upd_new = gx - c*(dx+dgx) - sum t_i u_i + c * sum q_i u_i  (in place: upd==dx)
// ---------------------------------------------------------------------------
__global__ __launch_bounds__(256) void pass2_kernel(
    unsigned short* __restrict__ Us, unsigned short* __restrict__ VTs,
    float* upd,
    const float* __restrict__ dgx, const float* __restrict__ gxn,
    const float* __restrict__ p, const float* __restrict__ q, const float* __restrict__ t,
    const float* __restrict__ denom, const float* __restrict__ c, int k)
{
    const int b = blockIdx.y;
    const int tid = threadIdx.x;
    __shared__ float sp[KMAX], sq[KMAX], st[KMAX];
    __shared__ float sden, sc;
    if (tid < k) {
        sp[tid] = p[b * KMAX + tid];
        sq[tid] = q[b * KMAX + tid];
        st[tid] = t[b * KMAX + tid];
    }
    if (tid == 0) { sden = denom[b]; sc = c[b]; }
    __syncthreads();

    const size_t base = (size_t)b * DDIM + ((size_t)blockIdx.x * 256 + tid) * 4;
    float4 vdx = *(const float4*)(upd + base);
    float4 vdg = *(const float4*)(dgx + base);
    float4 vg  = *(const float4*)(gxn + base);
    float xd[4] = {vdx.x, vdx.y, vdx.z, vdx.w};
    float dg[4] = {vdg.x, vdg.y, vdg.z, vdg.w};
    float gx[4] = {vg.x, vg.y, vg.z, vg.w};
    float S1[4] = {0,0,0,0}, S2[4] = {0,0,0,0}, SV[4] = {0,0,0,0};

    for (int i = 0; i < k; ++i) {
        ushort4 uu = *(const ushort4*)(Us  + (size_t)i * BDTOT + base);
        ushort4 vv = *(const ushort4*)(VTs + (size_t)i * BDTOT + base);
        float u0 = bf2f(uu.x), u1 = bf2f(uu.y), u2 = bf2f(uu.z), u3 = bf2f(uu.w);
        float v0 = bf2f(vv.x), v1 = bf2f(vv.y), v2 = bf2f(vv.z), v3 = bf2f(vv.w);
        float qi = sq[i], ti = st[i], pi = sp[i];
        S1[0] += qi * u0; S1[1] += qi * u1; S1[2] += qi * u2; S1[3] += qi * u3;
        S2[0] += ti * u0; S2[1] += ti * u1; S2[2] += ti * u2; S2[3] += ti * u3;
        SV[0] += pi * v0; SV[1] += pi * v1; SV[2] += pi * v2; SV[3] += pi * v3;
    }

    float vk[4], uk[4], up[4];
    #pragma unroll
    for (int j = 0; j < 4; ++j) {
        vk[j] = -xd[j] + SV[j];
        uk[j] = (xd[j] + dg[j] - S1[j]) / sden;
        up[j] = gx[j] - sc * (xd[j] + dg[j]) - S2[j] + sc * S1[j];
    }
    ushort4 vks, uks;
    vks.x = f2bf(vk[0]); vks.y = f2bf(vk[1]); vks.z = f2bf(vk[2]); vks.w = f2bf(vk[3]);
    uks.x = f2bf(uk[0]); uks.y = f2bf(uk[1]); uks.z = f2bf(uk[2]); uks.w = f2bf(uk[3]);
    *(ushort4*)(VTs + (size_t)k * BDTOT + base) = vks;
    *(ushort4*)(Us  + (size_t)k * BDTOT + base) = uks;
    *(float4*)(upd + base) = make_float4(up[0], up[1], up[2], up[3]);
}

// best_z (bf16 mirror) = zb when new best
__global__ __launch_bounds__(256) void bestcopy_kernel(
    const float* __restrict__ flag, const unsigned short* __restrict__ zb,
    unsigned short* __restrict__ bestzb)
{
    if (flag[0] == 0.f) return;
    size_t i = ((size_t)blockIdx.x * 256 + threadIdx.x) * 8;
    *(uint4*)(bestzb + i) = *(const uint4*)(zb + i);
}

// ---------------------------------------------------------------------------
extern "C" void kernel_launch(void* const* d_in, const int* in_sizes, int n_in,
                              void* d_out, int out_size, void* d_ws, size_t ws_size,
                              hipStream_t stream)
{
    (void)in_sizes; (void)n_in; (void)out_size; (void)ws_size;
    const float* x  = (const float*)d_in[0];   // [16,64,32,32]
    const float* A  = (const float*)d_in[1];   // [128,128,3,3]
    const float* U  = (const float*)d_in[2];   // [128,64,3,3]
    const float* bb = (const float*)d_in[3];   // [128]
    float* out = (float*)d_out;

    char* w = (char*)d_ws;
    size_t off = 0;
    auto alloc = [&](size_t bytes) -> void* {
        void* pp = (void*)(w + off);
        off += (bytes + 255) & ~(size_t)255;
        return pp;
    };
    const size_t BDB = BDTOT * sizeof(float);   // 8 MB
    float* ux    = (float*)alloc(BDB);          // NHWC fp32
    float* xv    = (float*)alloc(BDB);          // iterate x, NHWC fp32
    float* gx    = (float*)alloc(BDB);
    float* upd   = (float*)alloc(BDB);
    float* dgx   = (float*)alloc(BDB);
    unsigned short* zb     = (unsigned short*)alloc(BDTOT * 2);  // bf16 mirror of xv
    unsigned short* bestzb = (unsigned short*)alloc(BDTOT * 2);
    unsigned short* xinb   = (unsigned short*)alloc((size_t)NB * PLANE_ * CIN_ * 2);
    unsigned short* WA     = (unsigned short*)alloc((size_t)NWA * 2);
    unsigned short* WU     = (unsigned short*)alloc((size_t)NWU * 2);
    unsigned short* Us  = (unsigned short*)alloc((size_t)KMAX * BDTOT * 2); // 84 MB
    unsigned short* VTs = (unsigned short*)alloc((size_t)KMAX * BDTOT * 2); // 84 MB
    float* p     = (float*)alloc(NB * KMAX * sizeof(float));
    float* q     = (float*)alloc(NB * KMAX * sizeof(float));
    float* t     = (float*)alloc(NB * KMAX * sizeof(float));
    float* dd    = (float*)alloc(NB * sizeof(float));
    float* dg1   = (float*)alloc(NB * sizeof(float));
    float* objp  = (float*)alloc(NB * sizeof(float));
    float* denom = (float*)alloc(NB * sizeof(float));
    float* c     = (float*)alloc(NB * sizeof(float));
    float* best2 = (float*)alloc(sizeof(float));
    float* flag  = (float*)alloc(sizeof(float));

    const int EWG  = (int)(BDTOT / (256 * 4));  // 2048 blocks for fp32 D-vectors
    const int ZWG  = (int)(BDTOT / (256 * 4));  // zb as floats: BDTOT/2 floats /1024
    const dim3 CG(32, 4, NB);                   // mfma conv grid, 64-thr blocks

    // -------- one-time prep --------
    prep_w_kernel<<<(NWA + NWU + 255) / 256, 256, 0, stream>>>(A, U, WA, WU);
    prep_xin_kernel<<<(NB * PLANE_ * CIN_) / 256, 256, 0, stream>>>(x, xinb);
    fill0_kernel<<<EWG, 256, 0, stream>>>(xv);                 // x0 = 0
    fill0_kernel<<<ZWG / 2, 256, 0, stream>>>((float*)zb);     // zb = 0
    fill0_kernel<<<ZWG / 2, 256, 0, stream>>>((float*)bestzb); // best = x0 = 0

    // ux = conv(x,U) + b   (NHWC fp32)
    mfma_conv_kernel<0, CIN_><<<CG, 64, 0, stream>>>(xinb, WU, bb, nullptr, nullptr, ux, nullptr);
    // gx0 = relu(ux), update = gx0
    ew_init_kernel<<<EWG, 256, 0, stream>>>(ux, gx, upd);
    // best_obj = ||gx0||^2
    dots_kernel<<<dim3(NB, 1), 256, 0, stream>>>(Us, VTs, upd, dgx, gx,
                                                 p, q, t, dd, dg1, objp, 0, 1);
    small_kernel<<<1, 64, 0, stream>>>(p, q, t, dd, dg1, objp, denom, c, best2, flag, 0, 0);

    for (int k = 0; k < KMAX; ++k) {
        // x += update (dx == upd kept); zb = bf16(x)
        axpy_mirror_kernel<<<EWG, 256, 0, stream>>>(xv, upd, zb);
        // gx_new = relu(conv(x,A)+ux) - x ; dgx = gx_new - gx (gx in place)
        mfma_conv_kernel<1, COUT_><<<CG, 64, 0, stream>>>(zb, WA, nullptr, ux, xv, gx, dgx);
        if (k < KMAX - 1) {
            dots_kernel<<<dim3(NB, 2 * k + 2), 256, 0, stream>>>(
                Us, VTs, upd, dgx, gx, p, q, t, dd, dg1, objp, k, 0);
            small_kernel<<<1, 64, 0, stream>>>(p, q, t, dd, dg1, objp,
                                               denom, c, best2, flag, k, 1);
            pass2_kernel<<<dim3(EWG / NB, NB), 256, 0, stream>>>(
                Us, VTs, upd, dgx, gx, p, q, t, denom, c, k);
        } else {
            dots_kernel<<<dim3(NB, 1), 256, 0, stream>>>(
                Us, VTs, upd, dgx, gx, p, q, t, dd, dg1, objp, k, 1);
            small_kernel<<<1, 64, 0, stream>>>(p, q, t, dd, dg1, objp,
                                               denom, c, best2, flag, k, 2);
        }
        bestcopy_kernel<<<(int)(BDTOT / (256 * 8)), 256, 0, stream>>>(flag, zb, bestzb);
    }

    // zn = relu(conv(best_x,A) + ux)  -> NCHW out
    mfma_conv_kernel<2, COUT_><<<CG, 64, 0, stream>>>(bestzb, WA, nullptr, ux,
                                                      nullptr, out, nullptr);
}

// Round 4
// 1861.348 us; speedup vs baseline: 4.5081x; 1.2716x over previous
//
#include <hip/hip_runtime.h>

// Problem constants (fixed by reference setup_inputs)
#define NB    16              // batch
#define CIN_  64              // input channels of x
#define COUT_ 128             // channels of z / output
#define PLANE_ 1024           // 32*32
#define DDIM  (COUT_*PLANE_)  // 131072
#define BDTOT ((size_t)NB*DDIM) // 2097152
#define KMAX  20              // Broyden threshold
#define SMAX  8               // split-K factor for dots
#define SEG   (DDIM / SMAX)   // 16384 elems per split segment
#define GRP8  (SEG / 8)       // 2048 8-elem groups per segment
#define GRPF4 (SEG / 4)       // 4096 float4 per segment

typedef short  bfrag __attribute__((ext_vector_type(8)));  // 8 bf16 (4 VGPRs)
typedef float  ffrag __attribute__((ext_vector_type(4)));  // 4 fp32 acc

// bf16 <-> fp32 helpers (RNE)
__device__ __forceinline__ float bf2f(unsigned short h) {
    return __uint_as_float(((unsigned int)h) << 16);
}
__device__ __forceinline__ unsigned short f2bf(float f) {
    unsigned int u = __float_as_uint(f);
    u = (u + 0x7FFFu + ((u >> 16) & 1u)) >> 16;
    return (unsigned short)u;
}
// packed pair: word -> (elem0, elem1)
__device__ __forceinline__ void bf2x(unsigned int w, float& lo, float& hi) {
    lo = __uint_as_float(w << 16);
    hi = __uint_as_float(w & 0xffff0000u);
}
__device__ __forceinline__ unsigned int packbf(float lo, float hi) {
    return ((unsigned int)f2bf(hi) << 16) | (unsigned int)f2bf(lo);
}

// ---------------------------------------------------------------------------
// MFMA implicit-GEMM 3x3 SAME conv over NHWC bf16 input. (unchanged from R3)
// MODE 0: out = conv + bias[co]            -> ux   (fp32 NHWC)
// MODE 1: g = relu(conv+ux) - x ; dgx = g - gx_old  (gx in-place, fp32 NHWC)
// MODE 2: out = relu(conv+ux)              -> out  (fp32 NCHW!)
// grid: (32 px-tiles, 4 co-tiles, NB), block = 64.
// ---------------------------------------------------------------------------
template<int MODE, int CIN>
__global__ __launch_bounds__(64) void mfma_conv_kernel(
    const unsigned short* __restrict__ zb,
    const unsigned short* __restrict__ Wt,
    const float* __restrict__ bias,   // MODE 0
    const float* __restrict__ ux,     // MODE 1,2
    const float* __restrict__ xin,    // MODE 1 (fp32 iterate, NHWC)
    float* gx,                        // MODE 1 out (aliases gx_old), MODE 0/2: out
    float* __restrict__ dgx)          // MODE 1
{
    const int hrow    = blockIdx.x;
    const int co_base = blockIdx.y * 32;
    const int n       = blockIdx.z;
    const int lane    = threadIdx.x;
    const int col     = lane & 15;
    const int quad    = lane >> 4;

    ffrag acc00 = {0.f,0.f,0.f,0.f};
    ffrag acc01 = {0.f,0.f,0.f,0.f};
    ffrag acc10 = {0.f,0.f,0.f,0.f};
    ffrag acc11 = {0.f,0.f,0.f,0.f};
    const bfrag bzero = {0,0,0,0,0,0,0,0};

    const int w0 = col;
    const int w1 = col + 16;
    const size_t zbase = (size_t)n * PLANE_ * CIN;

    #pragma unroll
    for (int tap = 0; tap < 9; ++tap) {
        const int dh = tap / 3 - 1, dw = tap % 3 - 1;
        const int sh = hrow + dh;
        const bool rowok = (unsigned)sh < 32u;
        const int sw0 = w0 + dw, sw1 = w1 + dw;
        const bool v0 = rowok && (unsigned)sw0 < 32u;
        const bool v1 = rowok && (unsigned)sw1 < 32u;
        const int sp0 = v0 ? (sh * 32 + sw0) : (hrow * 32 + w0);
        const int sp1 = v1 ? (sh * 32 + sw1) : (hrow * 32 + w1);
        const unsigned short* z0 = zb + zbase + (size_t)sp0 * CIN + quad * 8;
        const unsigned short* z1 = zb + zbase + (size_t)sp1 * CIN + quad * 8;
        const unsigned short* wr0 = Wt + ((size_t)tap * COUT_ + co_base + col) * CIN + quad * 8;
        const unsigned short* wr1 = wr0 + 16 * CIN;
        #pragma unroll
        for (int cb = 0; cb < CIN; cb += 32) {
            bfrag a0 = *(const bfrag*)(wr0 + cb);
            bfrag a1 = *(const bfrag*)(wr1 + cb);
            bfrag b0 = *(const bfrag*)(z0 + cb);
            bfrag b1 = *(const bfrag*)(z1 + cb);
            if (!v0) b0 = bzero;
            if (!v1) b1 = bzero;
            acc00 = __builtin_amdgcn_mfma_f32_16x16x32_bf16(a0, b0, acc00, 0, 0, 0);
            acc01 = __builtin_amdgcn_mfma_f32_16x16x32_bf16(a0, b1, acc01, 0, 0, 0);
            acc10 = __builtin_amdgcn_mfma_f32_16x16x32_bf16(a1, b0, acc10, 0, 0, 0);
            acc11 = __builtin_amdgcn_mfma_f32_16x16x32_bf16(a1, b1, acc11, 0, 0, 0);
        }
    }

    #pragma unroll
    for (int mt = 0; mt < 2; ++mt) {
        #pragma unroll
        for (int nt = 0; nt < 2; ++nt) {
            ffrag a = (mt == 0) ? (nt == 0 ? acc00 : acc01)
                                : (nt == 0 ? acc10 : acc11);
            const int co = co_base + mt * 16 + quad * 4;
            const int px = hrow * 32 + nt * 16 + col;
            const size_t o = ((size_t)n * PLANE_ + px) * COUT_ + co; // NHWC
            if (MODE == 0) {
                float4 bv = *(const float4*)(bias + co);
                float4 r = {a[0] + bv.x, a[1] + bv.y, a[2] + bv.z, a[3] + bv.w};
                *(float4*)(gx + o) = r;
            } else if (MODE == 1) {
                float4 uv = *(const float4*)(ux + o);
                float4 xv = *(const float4*)(xin + o);
                float4 go = *(const float4*)(gx + o);
                float4 g, d;
                float t0 = a[0] + uv.x; t0 = t0 > 0.f ? t0 : 0.f; g.x = t0 - xv.x; d.x = g.x - go.x;
                float t1 = a[1] + uv.y; t1 = t1 > 0.f ? t1 : 0.f; g.y = t1 - xv.y; d.y = g.y - go.y;
                float t2 = a[2] + uv.z; t2 = t2 > 0.f ? t2 : 0.f; g.z = t2 - xv.z; d.z = g.z - go.z;
                float t3 = a[3] + uv.w; t3 = t3 > 0.f ? t3 : 0.f; g.w = t3 - xv.w; d.w = g.w - go.w;
                *(float4*)(gx + o) = g;
                *(float4*)(dgx + o) = d;
            } else {
                float4 uv = *(const float4*)(ux + o);
                #pragma unroll
                for (int r = 0; r < 4; ++r) {
                    float t = a[r] + (&uv.x)[r];
                    gx[((size_t)n * COUT_ + co + r) * PLANE_ + px] = t > 0.f ? t : 0.f;
                }
            }
        }
    }
}

// ---------------------------------------------------------------------------
// One-time prep: weights OIHW fp32 -> [tap][co][ci] bf16, x NCHW -> NHWC bf16.
// ---------------------------------------------------------------------------
#define NWA (9 * 128 * 128)
#define NWU (9 * 128 * 64)
__global__ __launch_bounds__(256) void prep_w_kernel(
    const float* __restrict__ A, const float* __restrict__ U,
    unsigned short* __restrict__ WA, unsigned short* __restrict__ WU)
{
    int idx = blockIdx.x * 256 + threadIdx.x;
    if (idx < NWA) {
        int tap = idx / (128 * 128), r = idx % (128 * 128);
        int co = r >> 7, ci = r & 127;
        WA[idx] = f2bf(A[(co * 128 + ci) * 9 + tap]);
    } else if (idx < NWA + NWU) {
        int j = idx - NWA;
        int tap = j / (128 * 64), r = j % (128 * 64);
        int co = r >> 6, ci = r & 63;
        WU[j] = f2bf(U[(co * 64 + ci) * 9 + tap]);
    }
}

__global__ __launch_bounds__(256) void prep_xin_kernel(
    const float* __restrict__ x, unsigned short* __restrict__ xb)
{
    int idx = blockIdx.x * 256 + threadIdx.x;   // over 16*1024*64
    int n = idx >> 16, r = idx & 65535;
    int px = r >> 6, ci = r & 63;
    xb[idx] = f2bf(x[(n * 64 + ci) * 1024 + px]);
}

__global__ __launch_bounds__(256) void fill0_kernel(float* __restrict__ a)
{
    size_t i = ((size_t)blockIdx.x * 256 + threadIdx.x) * 4;
    *(float4*)(a + i) = make_float4(0.f, 0.f, 0.f, 0.f);
}

// ---------------------------------------------------------------------------
// Init: x1 = gx0 = upd0 = relu(ux); zb = bf16(x1).  8 elems/thread.
// ---------------------------------------------------------------------------
__global__ __launch_bounds__(256) void ew_init_kernel(
    const float* __restrict__ ux, float* __restrict__ gx, float* __restrict__ upd,
    float* __restrict__ xv, unsigned short* __restrict__ zb)
{
    size_t i = ((size_t)blockIdx.x * 256 + threadIdx.x) * 8;
    float r[8];
    #pragma unroll
    for (int h = 0; h < 2; ++h) {
        float4 u = *(const float4*)(ux + i + h * 4);
        r[h*4+0] = u.x > 0.f ? u.x : 0.f;
        r[h*4+1] = u.y > 0.f ? u.y : 0.f;
        r[h*4+2] = u.z > 0.f ? u.z : 0.f;
        r[h*4+3] = u.w > 0.f ? u.w : 0.f;
    }
    #pragma unroll
    for (int h = 0; h < 2; ++h) {
        float4 v = {r[h*4+0], r[h*4+1], r[h*4+2], r[h*4+3]};
        *(float4*)(gx  + i + h * 4) = v;
        *(float4*)(upd + i + h * 4) = v;
        *(float4*)(xv  + i + h * 4) = v;
    }
    uint4 m = {packbf(r[0],r[1]), packbf(r[2],r[3]), packbf(r[4],r[5]), packbf(r[6],r[7])};
    *(uint4*)(zb + i) = m;
}

// ---------------------------------------------------------------------------
// Split-K batched dots. grid = (NB, Y, SMAX). Partial sums -> parts.
// y<k   : p_i  = u_i . dx
// y<2k  : q_i = v_i . dgx ; t_i = v_i . gx_new
// y==2k : dd  = dx . dgx  ; dg1 = dx . gx_new
// y==2k+1 (or only_obj): objpart = gx_new . gx_new
// parts[((y*NB+b)*SMAX+s)*2 + {0,1}]
// ---------------------------------------------------------------------------
__global__ __launch_bounds__(256) void dots_kernel(
    const unsigned short* __restrict__ Us, const unsigned short* __restrict__ VTs,
    const float* __restrict__ dx, const float* __restrict__ dgx,
    const float* __restrict__ gxn,
    float* __restrict__ parts, int k, int only_obj)
{
    const int b = blockIdx.x;
    const int y = blockIdx.y;
    const int s = blockIdx.z;
    const int tid = threadIdx.x;
    const size_t segbase = (size_t)b * DDIM + (size_t)s * SEG;

    int mode, i = 0;
    if (only_obj)          mode = 3;
    else if (y < k)        { mode = 0; i = y; }
    else if (y < 2 * k)    { mode = 1; i = y - k; }
    else if (y == 2 * k)   mode = 2;
    else                   mode = 3;

    float s0 = 0.f, s1 = 0.f;
    if (mode == 0) {
        const uint4*  u8 = (const uint4*)(Us + (size_t)i * BDTOT + segbase);
        const float4* xx = (const float4*)(dx + segbase);
        for (int g = tid; g < GRP8; g += 256) {
            uint4 a = u8[g];
            float4 x0 = xx[2*g], x1 = xx[2*g+1];
            float l, h;
            bf2x(a.x, l, h); s0 += l * x0.x + h * x0.y;
            bf2x(a.y, l, h); s0 += l * x0.z + h * x0.w;
            bf2x(a.z, l, h); s0 += l * x1.x + h * x1.y;
            bf2x(a.w, l, h); s0 += l * x1.z + h * x1.w;
        }
    } else if (mode == 1) {
        const uint4*  v8 = (const uint4*)(VTs + (size_t)i * BDTOT + segbase);
        const float4* gd = (const float4*)(dgx + segbase);
        const float4* gg = (const float4*)(gxn + segbase);
        for (int g = tid; g < GRP8; g += 256) {
            uint4 a = v8[g];
            float4 d0 = gd[2*g], d1 = gd[2*g+1];
            float4 n0 = gg[2*g], n1 = gg[2*g+1];
            float l, h;
            bf2x(a.x, l, h); s0 += l * d0.x + h * d0.y; s1 += l * n0.x + h * n0.y;
            bf2x(a.y, l, h); s0 += l * d0.z + h * d0.w; s1 += l * n0.z + h * n0.w;
            bf2x(a.z, l, h); s0 += l * d1.x + h * d1.y; s1 += l * n1.x + h * n1.y;
            bf2x(a.w, l, h); s0 += l * d1.z + h * d1.w; s1 += l * n1.z + h * n1.w;
        }
    } else if (mode == 2) {
        const float4* xx = (const float4*)(dx + segbase);
        const float4* gd = (const float4*)(dgx + segbase);
        const float4* gg = (const float4*)(gxn + segbase);
        for (int j = tid; j < GRPF4; j += 256) {
            float4 a = xx[j], g = gd[j], n = gg[j];
            s0 += a.x * g.x + a.y * g.y + a.z * g.z + a.w * g.w;
            s1 += a.x * n.x + a.y * n.y + a.z * n.z + a.w * n.w;
        }
    } else {
        const float4* gg = (const float4*)(gxn + segbase);
        for (int j = tid; j < GRPF4; j += 256) {
            float4 n = gg[j];
            s0 += n.x * n.x + n.y * n.y + n.z * n.z + n.w * n.w;
        }
    }

    __shared__ float r0[256], r1[256];
    r0[tid] = s0; r1[tid] = s1;
    __syncthreads();
    for (int st = 128; st > 0; st >>= 1) {
        if (tid < st) { r0[tid] += r0[tid + st]; r1[tid] += r1[tid + st]; }
        __syncthreads();
    }
    if (tid == 0) {
        size_t o = (((size_t)y * NB + b) * SMAX + s) * 2;
        parts[o]     = r0[0];
        parts[o + 1] = r1[0];
    }
}

// ---------------------------------------------------------------------------
// Fold split-K partials; per-iteration scalar math; best tracking.
// phase 0: init best from obj parts (y=0). phase 1: full. phase 2: obj only.
// ---------------------------------------------------------------------------
__global__ __launch_bounds__(256) void small_kernel(
    const float* __restrict__ parts,
    float* __restrict__ p, float* __restrict__ q, float* __restrict__ t,
    float* __restrict__ denom, float* __restrict__ c,
    float* __restrict__ best2, float* __restrict__ flag,
    int k, int phase)
{
    const int tid = threadIdx.x;
    if (phase == 1) {
        for (int idx = tid; idx < NB * k; idx += 256) {
            int b = idx / k, i = idx - b * k;
            float pv = 0.f, qv = 0.f, tv = 0.f;
            for (int s = 0; s < SMAX; ++s) {
                pv += parts[(((size_t)i * NB + b) * SMAX + s) * 2];
                qv += parts[((((size_t)k + i) * NB + b) * SMAX + s) * 2];
                tv += parts[((((size_t)k + i) * NB + b) * SMAX + s) * 2 + 1];
            }
            p[b * KMAX + i] = pv; q[b * KMAX + i] = qv; t[b * KMAX + i] = tv;
        }
        __syncthreads();
        if (tid < NB) {
            int b = tid;
            float ddv = 0.f, dgv = 0.f;
            for (int s = 0; s < SMAX; ++s) {
                ddv += parts[(((size_t)(2 * k) * NB + b) * SMAX + s) * 2];
                dgv += parts[(((size_t)(2 * k) * NB + b) * SMAX + s) * 2 + 1];
            }
            float pq = 0.f, pt = 0.f;
            for (int i = 0; i < k; ++i) {
                pq += p[b * KMAX + i] * q[b * KMAX + i];
                pt += p[b * KMAX + i] * t[b * KMAX + i];
            }
            float den = -ddv + pq;
            if (fabsf(den) < 1e-9f) den = 1e-9f;
            denom[b] = den;
            c[b] = (-dgv + pt) / den;
        }
    }
    __syncthreads();
    if (tid == 0) {
        int yobj = (phase == 1) ? (2 * k + 1) : 0;
        float o = 0.f;
        for (int b = 0; b < NB; ++b)
            for (int s = 0; s < SMAX; ++s)
                o += parts[(((size_t)yobj * NB + b) * SMAX + s) * 2];
        if (phase == 0) { *best2 = o; *flag = 0.f; }
        else {
            float bo = *best2;
            *flag = (o < bo) ? 1.f : 0.f;
            if (o < bo) *best2 = o;
        }
    }
}

// ---------------------------------------------------------------------------
// Fused big pass (one history read) + best snapshot + x advance + bf16 mirror.
// v_k = -dx + sum p_i v_i
// u_k = (dx + dgx - sum q_i u_i) / denom
// upd_new = gx - c*(dx+dgx) - sum t_i u_i + c * sum q_i u_i  (in place upd==dx)
// if flag: bestzb = bf16(x_cur)
// x_next = x_cur + upd_new ; xv = x_next ; zb = bf16(x_next)
// grid = (DDIM/2048, NB), 8 elems/thread.
// ---------------------------------------------------------------------------
__global__ __launch_bounds__(256) void pass2_kernel(
    unsigned short* __restrict__ Us, unsigned short* __restrict__ VTs,
    float* upd,
    const float* __restrict__ dgx, const float* __restrict__ gxn,
    float* xv, unsigned short* __restrict__ zb, unsigned short* __restrict__ bestzb,
    const float* __restrict__ p, const float* __restrict__ q, const float* __restrict__ t,
    const float* __restrict__ denom, const float* __restrict__ c,
    const float* __restrict__ flag, int k)
{
    const int b = blockIdx.y;
    const int tid = threadIdx.x;
    __shared__ float sp[KMAX], sq[KMAX], st[KMAX];
    __shared__ float sden, sc, sflag;
    if (tid < k) {
        sp[tid] = p[b * KMAX + tid];
        sq[tid] = q[b * KMAX + tid];
        st[tid] = t[b * KMAX + tid];
    }
    if (tid == 0) { sden = denom[b]; sc = c[b]; sflag = flag[0]; }
    __syncthreads();

    const size_t base = (size_t)b * DDIM + ((size_t)blockIdx.x * 256 + tid) * 8;
    float xd[8], dg[8], gv[8];
    #pragma unroll
    for (int h = 0; h < 2; ++h) {
        float4 a = *(const float4*)(upd + base + h * 4);
        float4 d = *(const float4*)(dgx + base + h * 4);
        float4 g = *(const float4*)(gxn + base + h * 4);
        xd[h*4+0]=a.x; xd[h*4+1]=a.y; xd[h*4+2]=a.z; xd[h*4+3]=a.w;
        dg[h*4+0]=d.x; dg[h*4+1]=d.y; dg[h*4+2]=d.z; dg[h*4+3]=d.w;
        gv[h*4+0]=g.x; gv[h*4+1]=g.y; gv[h*4+2]=g.z; gv[h*4+3]=g.w;
    }
    float S1[8], S2[8], SV[8];
    #pragma unroll
    for (int j = 0; j < 8; ++j) { S1[j]=0.f; S2[j]=0.f; SV[j]=0.f; }

    for (int i = 0; i < k; ++i) {
        uint4 uu = *(const uint4*)(Us  + (size_t)i * BDTOT + base);
        uint4 vv = *(const uint4*)(VTs + (size_t)i * BDTOT + base);
        float uvals[8], vvals[8];
        bf2x(uu.x, uvals[0], uvals[1]); bf2x(uu.y, uvals[2], uvals[3]);
        bf2x(uu.z, uvals[4], uvals[5]); bf2x(uu.w, uvals[6], uvals[7]);
        bf2x(vv.x, vvals[0], vvals[1]); bf2x(vv.y, vvals[2], vvals[3]);
        bf2x(vv.z, vvals[4], vvals[5]); bf2x(vv.w, vvals[6], vvals[7]);
        float qi = sq[i], ti = st[i], pi = sp[i];
        #pragma unroll
        for (int j = 0; j < 8; ++j) {
            S1[j] = fmaf(qi, uvals[j], S1[j]);
            S2[j] = fmaf(ti, uvals[j], S2[j]);
            SV[j] = fmaf(pi, vvals[j], SV[j]);
        }
    }

    float vk[8], uk[8], up[8];
    #pragma unroll
    for (int j = 0; j < 8; ++j) {
        vk[j] = -xd[j] + SV[j];
        uk[j] = (xd[j] + dg[j] - S1[j]) / sden;
        up[j] = gv[j] - sc * (xd[j] + dg[j]) - S2[j] + sc * S1[j];
    }
    uint4 vks = {packbf(vk[0],vk[1]), packbf(vk[2],vk[3]), packbf(vk[4],vk[5]), packbf(vk[6],vk[7])};
    uint4 uks = {packbf(uk[0],uk[1]), packbf(uk[2],uk[3]), packbf(uk[4],uk[5]), packbf(uk[6],uk[7])};
    *(uint4*)(VTs + (size_t)k * BDTOT + base) = vks;
    *(uint4*)(Us  + (size_t)k * BDTOT + base) = uks;

    // best snapshot of current x, then advance x
    float xc[8];
    #pragma unroll
    for (int h = 0; h < 2; ++h) {
        float4 a = *(const float4*)(xv + base + h * 4);
        xc[h*4+0]=a.x; xc[h*4+1]=a.y; xc[h*4+2]=a.z; xc[h*4+3]=a.w;
    }
    if (sflag != 0.f) {
        uint4 bz = {packbf(xc[0],xc[1]), packbf(xc[2],xc[3]),
                    packbf(xc[4],xc[5]), packbf(xc[6],xc[7])};
        *(uint4*)(bestzb + base) = bz;
    }
    float xn[8];
    #pragma unroll
    for (int j = 0; j < 8; ++j) xn[j] = xc[j] + up[j];
    #pragma unroll
    for (int h = 0; h < 2; ++h) {
        *(float4*)(xv  + base + h * 4) = make_float4(xn[h*4+0], xn[h*4+1], xn[h*4+2], xn[h*4+3]);
        *(float4*)(upd + base + h * 4) = make_float4(up[h*4+0], up[h*4+1], up[h*4+2], up[h*4+3]);
    }
    uint4 zn = {packbf(xn[0],xn[1]), packbf(xn[2],xn[3]), packbf(xn[4],xn[5]), packbf(xn[6],xn[7])};
    *(uint4*)(zb + base) = zn;
}

// best_z (bf16 mirror) = zb when new best (used only on the last iteration)
__global__ __launch_bounds__(256) void bestcopy_kernel(
    const float* __restrict__ flag, const unsigned short* __restrict__ zb,
    unsigned short* __restrict__ bestzb)
{
    if (flag[0] == 0.f) return;
    size_t i = ((size_t)blockIdx.x * 256 + threadIdx.x) * 8;
    *(uint4*)(bestzb + i) = *(const uint4*)(zb + i);
}

// ---------------------------------------------------------------------------
extern "C" void kernel_launch(void* const* d_in, const int* in_sizes, int n_in,
                              void* d_out, int out_size, void* d_ws, size_t ws_size,
                              hipStream_t stream)
{
    (void)in_sizes; (void)n_in; (void)out_size; (void)ws_size;
    const float* x  = (const float*)d_in[0];   // [16,64,32,32]
    const float* A  = (const float*)d_in[1];   // [128,128,3,3]
    const float* U  = (const float*)d_in[2];   // [128,64,3,3]
    const float* bb = (const float*)d_in[3];   // [128]
    float* out = (float*)d_out;

    char* w = (char*)d_ws;
    size_t off = 0;
    auto alloc = [&](size_t bytes) -> void* {
        void* pp = (void*)(w + off);
        off += (bytes + 255) & ~(size_t)255;
        return pp;
    };
    const size_t BDB = BDTOT * sizeof(float);   // 8 MB
    float* ux    = (float*)alloc(BDB);          // NHWC fp32
    float* xv    = (float*)alloc(BDB);          // iterate x, NHWC fp32
    float* gx    = (float*)alloc(BDB);
    float* upd   = (float*)alloc(BDB);
    float* dgx   = (float*)alloc(BDB);
    unsigned short* zb     = (unsigned short*)alloc(BDTOT * 2);  // bf16 mirror of xv
    unsigned short* bestzb = (unsigned short*)alloc(BDTOT * 2);
    unsigned short* xinb   = (unsigned short*)alloc((size_t)NB * PLANE_ * CIN_ * 2);
    unsigned short* WA     = (unsigned short*)alloc((size_t)NWA * 2);
    unsigned short* WU     = (unsigned short*)alloc((size_t)NWU * 2);
    unsigned short* Us  = (unsigned short*)alloc((size_t)KMAX * BDTOT * 2); // 84 MB
    unsigned short* VTs = (unsigned short*)alloc((size_t)KMAX * BDTOT * 2); // 84 MB
    float* parts = (float*)alloc((size_t)(2 * KMAX + 2) * NB * SMAX * 2 * sizeof(float));
    float* p     = (float*)alloc(NB * KMAX * sizeof(float));
    float* q     = (float*)alloc(NB * KMAX * sizeof(float));
    float* t     = (float*)alloc(NB * KMAX * sizeof(float));
    float* denom = (float*)alloc(NB * sizeof(float));
    float* c     = (float*)alloc(NB * sizeof(float));
    float* best2 = (float*)alloc(sizeof(float));
    float* flag  = (float*)alloc(sizeof(float));

    const dim3 CG(32, 4, NB);                   // mfma conv grid, 64-thr blocks
    const int I8WG = (int)(BDTOT / (256 * 8));  // 1024 blocks, 8 elems/thread

    // -------- one-time prep --------
    prep_w_kernel<<<(NWA + NWU + 255) / 256, 256, 0, stream>>>(A, U, WA, WU);
    prep_xin_kernel<<<(NB * PLANE_ * CIN_) / 256, 256, 0, stream>>>(x, xinb);
    fill0_kernel<<<(int)(BDTOT * 2 / (256 * 16)), 256, 0, stream>>>((float*)bestzb); // best=x0=0

    // ux = conv(x,U) + b   (NHWC fp32)
    mfma_conv_kernel<0, CIN_><<<CG, 64, 0, stream>>>(xinb, WU, bb, nullptr, nullptr, ux, nullptr);
    // x1 = gx0 = upd0 = relu(ux); zb = bf16(x1)
    ew_init_kernel<<<I8WG, 256, 0, stream>>>(ux, gx, upd, xv, zb);
    // best_obj = ||gx0||^2
    dots_kernel<<<dim3(NB, 1, SMAX), 256, 0, stream>>>(Us, VTs, upd, dgx, gx, parts, 0, 1);
    small_kernel<<<1, 256, 0, stream>>>(parts, p, q, t, denom, c, best2, flag, 0, 0);

    for (int k = 0; k < KMAX; ++k) {
        // gx_new = relu(conv(x_{k+1},A)+ux) - x_{k+1} ; dgx = gx_new - gx
        mfma_conv_kernel<1, COUT_><<<CG, 64, 0, stream>>>(zb, WA, nullptr, ux, xv, gx, dgx);
        if (k < KMAX - 1) {
            dots_kernel<<<dim3(NB, 2 * k + 2, SMAX), 256, 0, stream>>>(
                Us, VTs, upd, dgx, gx, parts, k, 0);
            small_kernel<<<1, 256, 0, stream>>>(parts, p, q, t, denom, c, best2, flag, k, 1);
            pass2_kernel<<<dim3(DDIM / 2048, NB), 256, 0, stream>>>(
                Us, VTs, upd, dgx, gx, xv, zb, bestzb, p, q, t, denom, c, flag, k);
        } else {
            dots_kernel<<<dim3(NB, 1, SMAX), 256, 0, stream>>>(
                Us, VTs, upd, dgx, gx, parts, k, 1);
            small_kernel<<<1, 256, 0, stream>>>(parts, p, q, t, denom, c, best2, flag, k, 2);
            bestcopy_kernel<<<I8WG, 256, 0, stream>>>(flag, zb, bestzb);
        }
    }

    // zn = relu(conv(best_x,A) + ux)  -> NCHW out
    mfma_conv_kernel<2, COUT_><<<CG, 64, 0, stream>>>(bestzb, WA, nullptr, ux,
                                                      nullptr, out, nullptr);
}